// Round 11
// baseline (543.653 us; speedup 1.0000x reference)
//
#include <hip/hip_runtime.h>

#define CDIM 192
#define NHEAD 6

typedef __bf16 bf16x8 __attribute__((ext_vector_type(8)));
typedef float f32x4 __attribute__((ext_vector_type(4)));

// ---- LDS: TWO window-halves of 78848 B each -> 157696 B total, 1 block/CU ----
// per half: q @0 (64x200 bf16), k @25600 (64x200), vt @51200 (192x72)
// aliases per half: P per-wave [16][72] @ q+wv*2304 (phase B; q dead)
//                   ao [64][200] @ k (phase B+; k dead)
//                   f32 out stage [64][196] @0 spans q+k (post-proj)
#define HB     78848
#define Q_OFF  0
#define K_OFF  25600
#define VT_OFF 51200
#define SMEM_BYTES (2 * HB)
#define QS  200
#define KS  200
#define VTS 72
#define AOS 200
#define PS  72
#define OFS 196
#define SCALE 0.17677669529663687f   // 32^-0.5

__device__ __forceinline__ unsigned short f2b(float f) {
    unsigned int u = __float_as_uint(f);
    u = (u + 0x7FFFu + ((u >> 16) & 1u)) >> 16;   // RNE
    return (unsigned short)u;
}

__device__ __forceinline__ bf16x8 cvt8(f32x4 a, f32x4 b) {
    bf16x8 r;
    r[0] = (__bf16)a[0]; r[1] = (__bf16)a[1]; r[2] = (__bf16)a[2]; r[3] = (__bf16)a[3];
    r[4] = (__bf16)b[0]; r[5] = (__bf16)b[1]; r[6] = (__bf16)b[2]; r[7] = (__bf16)b[3];
    return r;
}

// ---- d_ws layout (bytes) ----
#define WS_W1   0           // qkv_w bf16: 110592 u16 = 221184 B
#define WS_W2   221184      // proj_w bf16: 36864 u16 = 73728 B
#define WS_BIAS 294912      // bias f32: 6*64*64*4 = 98304 B (total 393216)

__global__ void prep(const float* __restrict__ qkv_w, const float* __restrict__ proj_w,
                     const float* __restrict__ rpb,
                     unsigned short* __restrict__ W1, unsigned short* __restrict__ W2,
                     float* __restrict__ BIAS) {
    int t = blockIdx.x * 256 + threadIdx.x;       // 0..172031
    if (t < 110592) { W1[t] = f2b(qkv_w[t]); return; }
    t -= 110592;
    if (t < 36864)  { W2[t] = f2b(proj_w[t]); return; }
    t -= 36864;
    {   // bias[h][i][j], 6*64*64 f32
        int h = t >> 12, ij = t & 4095;
        int i = ij >> 6, j = ij & 63;
        int idx = ((i >> 3) - (j >> 3) + 7) * 15 + ((i & 7) - (j & 7) + 7);
        BIAS[t] = rpb[idx * NHEAD + h];
    }
}

__global__ __launch_bounds__(512)
void win_attn(const float* __restrict__ x,
              const unsigned short* __restrict__ qkv_w,   // bf16 ws copy
              const float* __restrict__ qkv_b,
              const unsigned short* __restrict__ proj_w,  // bf16 ws copy
              const float* __restrict__ proj_b,
              const float* __restrict__ bias,
              float* __restrict__ out)
{
    extern __shared__ __align__(16) char smem[];

    const int tid  = threadIdx.x;
    const int wv   = tid >> 6;                  // wave 0..7
    const int lane = tid & 63;
    const int l15  = lane & 15;
    const int g    = lane >> 4;
    const int g4   = g << 2;
    const int g8   = g << 3;

    long long base[2];
    #pragma unroll
    for (int w = 0; w < 2; ++w) {
        int wid = blockIdx.x * 2 + w;           // 2048 blocks x 2 windows
        int b   = wid >> 10;
        int wy  = (wid >> 5) & 31;
        int wx  = wid & 31;
        base[w] = (long long)(b * 65536 + wy * 8 * 256 + wx * 8) * CDIM;
    }

    // ---------------- QKV GEMM: per-window pass, A direct from global x ----------------
    // acc[4][5] = 80 AGPR (spill-free, R7-proven); A addresses wave-invariant -> L1 broadcast.
    {
        const int qstart_lut[8] = {0, 5, 10, 15, 20, 25, 30, 31};
        const int start = qstart_lut[wv];

        #pragma unroll
        for (int w = 0; w < 2; ++w) {
            const float* xr[4];
            #pragma unroll
            for (int mt = 0; mt < 4; ++mt) {
                int t0 = mt * 16 + l15;
                xr[mt] = x + base[w] + ((t0 >> 3) * 256 + (t0 & 7)) * CDIM;
            }

            f32x4 acc[4][5];
            #pragma unroll
            for (int mt = 0; mt < 4; ++mt)
                #pragma unroll
                for (int jn = 0; jn < 5; ++jn)
                    acc[mt][jn] = (f32x4){0.f, 0.f, 0.f, 0.f};

            #pragma unroll
            for (int kk = 0; kk < 6; ++kk) {
                bf16x8 aa[4];
                #pragma unroll
                for (int mt = 0; mt < 4; ++mt) {
                    f32x4 lo = *(const f32x4*)(xr[mt] + kk * 32 + g8);
                    f32x4 hi = *(const f32x4*)(xr[mt] + kk * 32 + g8 + 4);
                    aa[mt] = cvt8(lo, hi);
                }
                #pragma unroll
                for (int jn = 0; jn < 5; ++jn) {
                    int o = (start + jn) * 16 + l15;
                    bf16x8 bw = *(const bf16x8*)((const __bf16*)qkv_w + o * CDIM + kk * 32 + g8);
                    #pragma unroll
                    for (int mt = 0; mt < 4; ++mt)
                        acc[mt][jn] = __builtin_amdgcn_mfma_f32_16x16x32_bf16(aa[mt], bw, acc[mt][jn], 0, 0, 0);
                }
            }
            // stores: q,k token-major; v transposed (no LDS conflicts: x not staged)
            __bf16* ql  = (__bf16*)(smem + w * HB + Q_OFF);
            __bf16* kl  = (__bf16*)(smem + w * HB + K_OFF);
            __bf16* vtw = (__bf16*)(smem + w * HB + VT_OFF);
            #pragma unroll
            for (int jn = 0; jn < 5; ++jn) {
                int nt = start + jn;            // 0..35
                int o  = nt * 16 + l15;         // 0..575
                float qb = qkv_b[o];
                #pragma unroll
                for (int mt = 0; mt < 4; ++mt) {
                    #pragma unroll
                    for (int rr = 0; rr < 4; ++rr) {
                        int tr = mt * 16 + g4 + rr;
                        float val = acc[mt][jn][rr] + qb;
                        if (nt < 12)       ql[tr * QS + o] = (__bf16)val;
                        else if (nt < 24)  kl[tr * KS + (o - 192)] = (__bf16)val;
                        else               vtw[(o - 384) * VTS + tr] = (__bf16)val;
                    }
                }
            }
        }
    }
    __syncthreads();   // bar1: q,k,vt ready (both windows)

    // ---------------- attention: A0 | bar | B0,A1 | bar | B1 ----------------
    f32x4 sh[3][4];    // one window's P at a time (48 regs)

#define ATTN_A(w) { \
        const __bf16* ql = (const __bf16*)(smem + (w) * HB + Q_OFF); \
        const __bf16* kl = (const __bf16*)(smem + (w) * HB + K_OFF); \
        _Pragma("unroll") \
        for (int u = 0; u < 3; ++u) { \
            int gu = wv * 3 + u; \
            int hu = gu >> 2; \
            int rb = gu & 3; \
            bf16x8 aq = *(const bf16x8*)(ql + (rb * 16 + l15) * QS + hu * 32 + g8); \
            _Pragma("unroll") \
            for (int ni = 0; ni < 4; ++ni) { \
                bf16x8 bk = *(const bf16x8*)(kl + (ni * 16 + l15) * KS + hu * 32 + g8); \
                sh[u][ni] = __builtin_amdgcn_mfma_f32_16x16x32_bf16(aq, bk, (f32x4){0.f, 0.f, 0.f, 0.f}, 0, 0, 0); \
            } \
            const float* brow = bias + hu * 4096; \
            _Pragma("unroll") \
            for (int rr = 0; rr < 4; ++rr) { \
                int row = rb * 16 + g4 + rr; \
                float v0 = sh[u][0][rr] * SCALE + brow[row * 64 +  0 + l15]; \
                float v1 = sh[u][1][rr] * SCALE + brow[row * 64 + 16 + l15]; \
                float v2 = sh[u][2][rr] * SCALE + brow[row * 64 + 32 + l15]; \
                float v3 = sh[u][3][rr] * SCALE + brow[row * 64 + 48 + l15]; \
                float m = fmaxf(fmaxf(v0, v1), fmaxf(v2, v3)); \
                m = fmaxf(m, __shfl_xor(m, 1)); \
                m = fmaxf(m, __shfl_xor(m, 2)); \
                m = fmaxf(m, __shfl_xor(m, 4)); \
                m = fmaxf(m, __shfl_xor(m, 8)); \
                v0 = __expf(v0 - m); v1 = __expf(v1 - m); \
                v2 = __expf(v2 - m); v3 = __expf(v3 - m); \
                float s = v0 + v1 + v2 + v3; \
                s += __shfl_xor(s, 1); s += __shfl_xor(s, 2); \
                s += __shfl_xor(s, 4); s += __shfl_xor(s, 8); \
                float inv = 1.0f / s; \
                sh[u][0][rr] = v0 * inv; \
                sh[u][1][rr] = v1 * inv; \
                sh[u][2][rr] = v2 * inv; \
                sh[u][3][rr] = v3 * inv; \
            } \
        } \
    }

#define ATTN_B(w) { \
        __bf16* ph  = (__bf16*)(smem + (w) * HB + Q_OFF) + wv * (16 * PS); \
        const __bf16* vtw = (const __bf16*)(smem + (w) * HB + VT_OFF); \
        __bf16* aob = (__bf16*)(smem + (w) * HB + K_OFF); \
        _Pragma("unroll") \
        for (int u = 0; u < 3; ++u) { \
            int gu = wv * 3 + u; \
            int hu = gu >> 2; \
            int rb = gu & 3; \
            _Pragma("unroll") \
            for (int rr = 0; rr < 4; ++rr) { \
                int pr = (g4 + rr) * PS; \
                ph[pr +  0 + l15] = (__bf16)sh[u][0][rr]; \
                ph[pr + 16 + l15] = (__bf16)sh[u][1][rr]; \
                ph[pr + 32 + l15] = (__bf16)sh[u][2][rr]; \
                ph[pr + 48 + l15] = (__bf16)sh[u][3][rr]; \
            } \
            __threadfence_block(); \
            f32x4 oacc[2]; \
            oacc[0] = (f32x4){0.f, 0.f, 0.f, 0.f}; \
            oacc[1] = (f32x4){0.f, 0.f, 0.f, 0.f}; \
            _Pragma("unroll") \
            for (int kk = 0; kk < 2; ++kk) { \
                bf16x8 pa = *(const bf16x8*)(ph + l15 * PS + kk * 32 + g8); \
                _Pragma("unroll") \
                for (int nj = 0; nj < 2; ++nj) { \
                    bf16x8 bv = *(const bf16x8*)(vtw + (hu * 32 + nj * 16 + l15) * VTS + kk * 32 + g8); \
                    oacc[nj] = __builtin_amdgcn_mfma_f32_16x16x32_bf16(pa, bv, oacc[nj], 0, 0, 0); \
                } \
            } \
            __threadfence_block(); \
            _Pragma("unroll") \
            for (int nj = 0; nj < 2; ++nj) \
                _Pragma("unroll") \
                for (int rr = 0; rr < 4; ++rr) \
                    aob[(rb * 16 + g4 + rr) * AOS + hu * 32 + nj * 16 + l15] = (__bf16)oacc[nj][rr]; \
        } \
    }

    ATTN_A(0)
    __syncthreads();   // bar2: q(w0)/k(w0) reads done -> B0 may overwrite them
    ATTN_B(0)          // writes P(w0), ao(w0)
    ATTN_A(1)          // disjoint regions: q(w1)/k(w1)
    __syncthreads();   // bar3: B0 stores + A1 reads done
    ATTN_B(1)
    __syncthreads();   // bar4: ao complete (both)

    // ---------------- proj GEMM: both windows, bw shared ----------------
    {
        const int pstart_lut[8] = {0, 2, 4, 6, 8, 10, 10, 10};
        const int start = pstart_lut[wv];

        f32x4 pacc[2][4][2];
        #pragma unroll
        for (int w = 0; w < 2; ++w)
            #pragma unroll
            for (int mt = 0; mt < 4; ++mt)
                #pragma unroll
                for (int jn = 0; jn < 2; ++jn)
                    pacc[w][mt][jn] = (f32x4){0.f, 0.f, 0.f, 0.f};

        #pragma unroll
        for (int kk = 0; kk < 6; ++kk) {
            bf16x8 bw[2];
            #pragma unroll
            for (int jn = 0; jn < 2; ++jn) {
                int o = (start + jn) * 16 + l15;
                bw[jn] = *(const bf16x8*)((const __bf16*)proj_w + o * CDIM + kk * 32 + g8);
            }
            #pragma unroll
            for (int w = 0; w < 2; ++w) {
                const __bf16* aob = (const __bf16*)(smem + w * HB + K_OFF);
                bf16x8 aa[4];
                #pragma unroll
                for (int mt = 0; mt < 4; ++mt)
                    aa[mt] = *(const bf16x8*)(aob + (mt * 16 + l15) * AOS + kk * 32 + g8);
                #pragma unroll
                for (int jn = 0; jn < 2; ++jn)
                    #pragma unroll
                    for (int mt = 0; mt < 4; ++mt)
                        pacc[w][mt][jn] = __builtin_amdgcn_mfma_f32_16x16x32_bf16(aa[mt], bw[jn], pacc[w][mt][jn], 0, 0, 0);
            }
        }
        __syncthreads();   // bar5: proj reads done -> q+k regions free for f32 stage

        #pragma unroll
        for (int jn = 0; jn < 2; ++jn) {
            int o = (start + jn) * 16 + l15;
            float pb = proj_b[o];
            #pragma unroll
            for (int w = 0; w < 2; ++w) {
                float* stagef = (float*)(smem + w * HB);
                #pragma unroll
                for (int mt = 0; mt < 4; ++mt)
                    #pragma unroll
                    for (int rr = 0; rr < 4; ++rr) {
                        int tr = mt * 16 + g4 + rr;
                        stagef[tr * OFS + o] = pacc[w][mt][jn][rr] + pb;
                    }
            }
        }
    }
    __syncthreads();   // bar6: stage complete

    // ---------------- window-reverse coalesced f32 store (both) ----------------
    #pragma unroll
    for (int w = 0; w < 2; ++w) {
        const float* stagef = (const float*)(smem + w * HB);
        #pragma unroll
        for (int r = 0; r < 6; ++r) {
            int i = tid + r * 512;
            int t = i / 48, part = i - t * 48;
            int iy = t >> 3, ix = t & 7;
            *(f32x4*)(out + base[w] + (iy * 256 + ix) * CDIM + part * 4) =
                *(const f32x4*)(stagef + t * OFS + part * 4);
        }
    }
#undef ATTN_A
#undef ATTN_B
}

extern "C" void kernel_launch(void* const* d_in, const int* in_sizes, int n_in,
                              void* d_out, int out_size, void* d_ws, size_t ws_size,
                              hipStream_t stream) {
    const float* x      = (const float*)d_in[0];
    const float* qkv_w  = (const float*)d_in[1];
    const float* qkv_b  = (const float*)d_in[2];
    const float* proj_w = (const float*)d_in[3];
    const float* proj_b = (const float*)d_in[4];
    const float* rpb    = (const float*)d_in[5];
    float* outp = (float*)d_out;

    char* ws = (char*)d_ws;
    unsigned short* W1 = (unsigned short*)(ws + WS_W1);
    unsigned short* W2 = (unsigned short*)(ws + WS_W2);
    float* BIAS = (float*)(ws + WS_BIAS);

    hipFuncSetAttribute((const void*)win_attn,
                        hipFuncAttributeMaxDynamicSharedMemorySize, SMEM_BYTES);

    prep<<<672, 256, 0, stream>>>(qkv_w, proj_w, rpb, W1, W2, BIAS);
    win_attn<<<2048, 512, SMEM_BYTES, stream>>>(x, W1, qkv_b, W2, proj_b, BIAS, outp);
}

// Round 12
// 369.997 us; speedup vs baseline: 1.4693x; 1.4693x over previous
//
#include <hip/hip_runtime.h>

#define CDIM 192
#define NHEAD 6

typedef __bf16 bf16x8 __attribute__((ext_vector_type(8)));
typedef float f32x4 __attribute__((ext_vector_type(4)));

// ---- LDS: TWO window-halves of 78848 B each -> 157696 B total, 1 block/CU ----
// per half: q @0 (64x200 bf16), k @25600 (64x200, holds x during QKV), vt @51200 (192x72)
// aliases per half: P per-wave [16][72] @ q+wv*2304 (PV; q dead), ao @k (post-attn),
//                   f32 out stage [64][196] @0 spans q+k (post-proj)
#define HB     78848
#define Q_OFF  0
#define K_OFF  25600
#define VT_OFF 51200
#define SMEM_BYTES (2 * HB)
#define XS  200
#define QS  200
#define KS  200
#define VTS 72
#define AOS 200
#define PS  72
#define OFS 196
#define SCALE 0.17677669529663687f   // 32^-0.5

__device__ __forceinline__ unsigned short f2b(float f) {
    unsigned int u = __float_as_uint(f);
    u = (u + 0x7FFFu + ((u >> 16) & 1u)) >> 16;   // RNE
    return (unsigned short)u;
}

// ---- d_ws layout (bytes) ----
#define WS_W1   0           // qkv_w bf16: 110592 u16 = 221184 B
#define WS_W2   221184      // proj_w bf16: 36864 u16 = 73728 B
#define WS_BIAS 294912      // bias f32: 6*64*64*4 = 98304 B (total 393216)

__global__ void prep(const float* __restrict__ qkv_w, const float* __restrict__ proj_w,
                     const float* __restrict__ rpb,
                     unsigned short* __restrict__ W1, unsigned short* __restrict__ W2,
                     float* __restrict__ BIAS) {
    int t = blockIdx.x * 256 + threadIdx.x;       // 0..172031
    if (t < 110592) { W1[t] = f2b(qkv_w[t]); return; }
    t -= 110592;
    if (t < 36864)  { W2[t] = f2b(proj_w[t]); return; }
    t -= 36864;
    {   // bias[h][i][j], 6*64*64 f32
        int h = t >> 12, ij = t & 4095;
        int i = ij >> 6, j = ij & 63;
        int idx = ((i >> 3) - (j >> 3) + 7) * 15 + ((i & 7) - (j & 7) + 7);
        BIAS[t] = rpb[idx * NHEAD + h];
    }
}

__global__ __launch_bounds__(512)
void win_attn(const float* __restrict__ x,
              const unsigned short* __restrict__ qkv_w,   // bf16 ws copy
              const float* __restrict__ qkv_b,
              const unsigned short* __restrict__ proj_w,  // bf16 ws copy
              const float* __restrict__ proj_b,
              const float* __restrict__ bias,
              float* __restrict__ out)
{
    extern __shared__ __align__(16) char smem[];

    const int tid  = threadIdx.x;
    const int wv   = tid >> 6;                  // wave 0..7
    const int lane = tid & 63;
    const int l15  = lane & 15;
    const int g    = lane >> 4;
    const int g4   = g << 2;
    const int g8   = g << 3;

    long long base[2];
    #pragma unroll
    for (int w = 0; w < 2; ++w) {
        int wid = blockIdx.x * 2 + w;           // 2048 blocks x 2 windows
        int b   = wid >> 10;
        int wy  = (wid >> 5) & 31;
        int wx  = wid & 31;
        base[w] = (long long)(b * 65536 + wy * 8 * 256 + wx * 8) * CDIM;
    }

    // ---------------- stage x (f32 -> bf16) into each half's k-region ----------------
    #pragma unroll
    for (int w = 0; w < 2; ++w) {
        __bf16* xk = (__bf16*)(smem + w * HB + K_OFF);
        #pragma unroll
        for (int r = 0; r < 6; ++r) {
            int i = tid + r * 512;              // 3072 f32x4 chunks
            int t = i / 48, part = i - t * 48;
            int iy = t >> 3, ix = t & 7;
            f32x4 v = *(const f32x4*)(x + base[w] + (iy * 256 + ix) * CDIM + part * 4);
            __bf16* dst = xk + t * XS + part * 4;
            dst[0] = (__bf16)v[0]; dst[1] = (__bf16)v[1];
            dst[2] = (__bf16)v[2]; dst[3] = (__bf16)v[3];
        }
    }
    __syncthreads();   // S0: both x staged

    // ---------------- QKV GEMM: 2 M-passes x 2 windows, bw shared (1 load -> 4 MFMAs) ----
    // acc[2][2][5] = 80 regs (spill-free). Pass mp reads x rows [mp*32,mp*32+32) and,
    // after a barrier, overwrites exactly those rows with k -- bands disjoint across passes.
    {
        const int qstart_lut[8] = {0, 5, 10, 15, 20, 25, 30, 31};
        const int start = qstart_lut[wv];

        #pragma unroll
        for (int mp = 0; mp < 2; ++mp) {
            f32x4 acc[2][2][5];
            #pragma unroll
            for (int w = 0; w < 2; ++w)
                #pragma unroll
                for (int im = 0; im < 2; ++im)
                    #pragma unroll
                    for (int jn = 0; jn < 5; ++jn)
                        acc[w][im][jn] = (f32x4){0.f, 0.f, 0.f, 0.f};

            #pragma unroll
            for (int kk = 0; kk < 6; ++kk) {
                bf16x8 aa[2][2];
                #pragma unroll
                for (int w = 0; w < 2; ++w) {
                    const __bf16* xk = (const __bf16*)(smem + w * HB + K_OFF);
                    #pragma unroll
                    for (int im = 0; im < 2; ++im)
                        aa[w][im] = *(const bf16x8*)(xk + ((mp * 2 + im) * 16 + l15) * XS + kk * 32 + g8);
                }
                #pragma unroll
                for (int jn = 0; jn < 5; ++jn) {
                    int o = (start + jn) * 16 + l15;
                    bf16x8 bw = *(const bf16x8*)((const __bf16*)qkv_w + o * CDIM + kk * 32 + g8);
                    #pragma unroll
                    for (int w = 0; w < 2; ++w)
                        #pragma unroll
                        for (int im = 0; im < 2; ++im)
                            acc[w][im][jn] = __builtin_amdgcn_mfma_f32_16x16x32_bf16(aa[w][im], bw, acc[w][im][jn], 0, 0, 0);
                }
            }
            __syncthreads();   // all waves done reading x band mp -> its rows writable

            #pragma unroll
            for (int jn = 0; jn < 5; ++jn) {
                int nt = start + jn;            // 0..35
                int o  = nt * 16 + l15;         // 0..575
                float qb = qkv_b[o];
                #pragma unroll
                for (int w = 0; w < 2; ++w) {
                    __bf16* ql  = (__bf16*)(smem + w * HB + Q_OFF);
                    __bf16* kl  = (__bf16*)(smem + w * HB + K_OFF);
                    __bf16* vtw = (__bf16*)(smem + w * HB + VT_OFF);
                    #pragma unroll
                    for (int im = 0; im < 2; ++im) {
                        #pragma unroll
                        for (int rr = 0; rr < 4; ++rr) {
                            int tr = (mp * 2 + im) * 16 + g4 + rr;   // in band mp
                            float val = acc[w][im][jn][rr] + qb;
                            if (nt < 12)       ql[tr * QS + o] = (__bf16)val;
                            else if (nt < 24)  kl[tr * KS + (o - 192)] = (__bf16)val;
                            else               vtw[(o - 384) * VTS + tr] = (__bf16)val;
                        }
                    }
                }
            }
            // next pass's MFMAs read x band mp+1 (disjoint from this pass's k-band writes)
        }
    }
    __syncthreads();   // Q1: q,k,vt ready (both windows)

    // ---------------- attention: A0 | bar | B0 ‖ A1 | bar | B1 ----------------
    f32x4 sh[3][4];    // one window's P at a time (48 regs)

#define ATTN_A(w) { \
        const __bf16* ql = (const __bf16*)(smem + (w) * HB + Q_OFF); \
        const __bf16* kl = (const __bf16*)(smem + (w) * HB + K_OFF); \
        _Pragma("unroll") \
        for (int u = 0; u < 3; ++u) { \
            int gu = wv * 3 + u; \
            int hu = gu >> 2; \
            int rb = gu & 3; \
            bf16x8 aq = *(const bf16x8*)(ql + (rb * 16 + l15) * QS + hu * 32 + g8); \
            _Pragma("unroll") \
            for (int ni = 0; ni < 4; ++ni) { \
                bf16x8 bk = *(const bf16x8*)(kl + (ni * 16 + l15) * KS + hu * 32 + g8); \
                sh[u][ni] = __builtin_amdgcn_mfma_f32_16x16x32_bf16(aq, bk, (f32x4){0.f, 0.f, 0.f, 0.f}, 0, 0, 0); \
            } \
            const float* brow = bias + hu * 4096; \
            _Pragma("unroll") \
            for (int rr = 0; rr < 4; ++rr) { \
                int row = rb * 16 + g4 + rr; \
                float v0 = sh[u][0][rr] * SCALE + brow[row * 64 +  0 + l15]; \
                float v1 = sh[u][1][rr] * SCALE + brow[row * 64 + 16 + l15]; \
                float v2 = sh[u][2][rr] * SCALE + brow[row * 64 + 32 + l15]; \
                float v3 = sh[u][3][rr] * SCALE + brow[row * 64 + 48 + l15]; \
                float m = fmaxf(fmaxf(v0, v1), fmaxf(v2, v3)); \
                m = fmaxf(m, __shfl_xor(m, 1)); \
                m = fmaxf(m, __shfl_xor(m, 2)); \
                m = fmaxf(m, __shfl_xor(m, 4)); \
                m = fmaxf(m, __shfl_xor(m, 8)); \
                v0 = __expf(v0 - m); v1 = __expf(v1 - m); \
                v2 = __expf(v2 - m); v3 = __expf(v3 - m); \
                float s = v0 + v1 + v2 + v3; \
                s += __shfl_xor(s, 1); s += __shfl_xor(s, 2); \
                s += __shfl_xor(s, 4); s += __shfl_xor(s, 8); \
                float inv = 1.0f / s; \
                sh[u][0][rr] = v0 * inv; \
                sh[u][1][rr] = v1 * inv; \
                sh[u][2][rr] = v2 * inv; \
                sh[u][3][rr] = v3 * inv; \
            } \
        } \
    }

#define ATTN_B(w) { \
        __bf16* ph  = (__bf16*)(smem + (w) * HB + Q_OFF) + wv * (16 * PS); \
        const __bf16* vtw = (const __bf16*)(smem + (w) * HB + VT_OFF); \
        __bf16* aob = (__bf16*)(smem + (w) * HB + K_OFF); \
        _Pragma("unroll") \
        for (int u = 0; u < 3; ++u) { \
            int gu = wv * 3 + u; \
            int hu = gu >> 2; \
            int rb = gu & 3; \
            _Pragma("unroll") \
            for (int rr = 0; rr < 4; ++rr) { \
                int pr = (g4 + rr) * PS; \
                ph[pr +  0 + l15] = (__bf16)sh[u][0][rr]; \
                ph[pr + 16 + l15] = (__bf16)sh[u][1][rr]; \
                ph[pr + 32 + l15] = (__bf16)sh[u][2][rr]; \
                ph[pr + 48 + l15] = (__bf16)sh[u][3][rr]; \
            } \
            __threadfence_block(); \
            f32x4 oacc[2]; \
            oacc[0] = (f32x4){0.f, 0.f, 0.f, 0.f}; \
            oacc[1] = (f32x4){0.f, 0.f, 0.f, 0.f}; \
            _Pragma("unroll") \
            for (int kk = 0; kk < 2; ++kk) { \
                bf16x8 pa = *(const bf16x8*)(ph + l15 * PS + kk * 32 + g8); \
                _Pragma("unroll") \
                for (int nj = 0; nj < 2; ++nj) { \
                    bf16x8 bv = *(const bf16x8*)(vtw + (hu * 32 + nj * 16 + l15) * VTS + kk * 32 + g8); \
                    oacc[nj] = __builtin_amdgcn_mfma_f32_16x16x32_bf16(pa, bv, oacc[nj], 0, 0, 0); \
                } \
            } \
            __threadfence_block(); \
            _Pragma("unroll") \
            for (int nj = 0; nj < 2; ++nj) \
                _Pragma("unroll") \
                for (int rr = 0; rr < 4; ++rr) \
                    aob[(rb * 16 + g4 + rr) * AOS + hu * 32 + nj * 16 + l15] = (__bf16)oacc[nj][rr]; \
        } \
    }

    ATTN_A(0)
    __syncthreads();   // A0's q/k(w0) reads done -> B0 may overwrite
    ATTN_B(0)          // writes P(w0) in q(w0), ao(w0) in k(w0)
    ATTN_A(1)          // reads q/k(w1): disjoint from B0's regions
    __syncthreads();   // B0 stores + A1 reads done
    ATTN_B(1)
    __syncthreads();   // ao complete (both)

    // ---------------- proj GEMM: both windows, bw shared ----------------
    {
        const int pstart_lut[8] = {0, 2, 4, 6, 8, 10, 10, 10};
        const int start = pstart_lut[wv];

        f32x4 pacc[2][4][2];
        #pragma unroll
        for (int w = 0; w < 2; ++w)
            #pragma unroll
            for (int mt = 0; mt < 4; ++mt)
                #pragma unroll
                for (int jn = 0; jn < 2; ++jn)
                    pacc[w][mt][jn] = (f32x4){0.f, 0.f, 0.f, 0.f};

        #pragma unroll
        for (int kk = 0; kk < 6; ++kk) {
            bf16x8 bw[2];
            #pragma unroll
            for (int jn = 0; jn < 2; ++jn) {
                int o = (start + jn) * 16 + l15;
                bw[jn] = *(const bf16x8*)((const __bf16*)proj_w + o * CDIM + kk * 32 + g8);
            }
            #pragma unroll
            for (int w = 0; w < 2; ++w) {
                const __bf16* aob = (const __bf16*)(smem + w * HB + K_OFF);
                bf16x8 aa[4];
                #pragma unroll
                for (int mt = 0; mt < 4; ++mt)
                    aa[mt] = *(const bf16x8*)(aob + (mt * 16 + l15) * AOS + kk * 32 + g8);
                #pragma unroll
                for (int jn = 0; jn < 2; ++jn)
                    #pragma unroll
                    for (int mt = 0; mt < 4; ++mt)
                        pacc[w][mt][jn] = __builtin_amdgcn_mfma_f32_16x16x32_bf16(aa[mt], bw[jn], pacc[w][mt][jn], 0, 0, 0);
            }
        }
        __syncthreads();   // proj reads done -> q+k regions free for f32 stage

        #pragma unroll
        for (int jn = 0; jn < 2; ++jn) {
            int o = (start + jn) * 16 + l15;
            float pb = proj_b[o];
            #pragma unroll
            for (int w = 0; w < 2; ++w) {
                float* stagef = (float*)(smem + w * HB);
                #pragma unroll
                for (int mt = 0; mt < 4; ++mt)
                    #pragma unroll
                    for (int rr = 0; rr < 4; ++rr) {
                        int tr = mt * 16 + g4 + rr;
                        stagef[tr * OFS + o] = pacc[w][mt][jn][rr] + pb;
                    }
            }
        }
    }
    __syncthreads();   // stage complete

    // ---------------- window-reverse coalesced f32 store (both) ----------------
    #pragma unroll
    for (int w = 0; w < 2; ++w) {
        const float* stagef = (const float*)(smem + w * HB);
        #pragma unroll
        for (int r = 0; r < 6; ++r) {
            int i = tid + r * 512;
            int t = i / 48, part = i - t * 48;
            int iy = t >> 3, ix = t & 7;
            *(f32x4*)(out + base[w] + (iy * 256 + ix) * CDIM + part * 4) =
                *(const f32x4*)(stagef + t * OFS + part * 4);
        }
    }
#undef ATTN_A
#undef ATTN_B
}

extern "C" void kernel_launch(void* const* d_in, const int* in_sizes, int n_in,
                              void* d_out, int out_size, void* d_ws, size_t ws_size,
                              hipStream_t stream) {
    const float* x      = (const float*)d_in[0];
    const float* qkv_w  = (const float*)d_in[1];
    const float* qkv_b  = (const float*)d_in[2];
    const float* proj_w = (const float*)d_in[3];
    const float* proj_b = (const float*)d_in[4];
    const float* rpb    = (const float*)d_in[5];
    float* outp = (float*)d_out;

    char* ws = (char*)d_ws;
    unsigned short* W1 = (unsigned short*)(ws + WS_W1);
    unsigned short* W2 = (unsigned short*)(ws + WS_W2);
    float* BIAS = (float*)(ws + WS_BIAS);

    hipFuncSetAttribute((const void*)win_attn,
                        hipFuncAttributeMaxDynamicSharedMemorySize, SMEM_BYTES);

    prep<<<672, 256, 0, stream>>>(qkv_w, proj_w, rpb, W1, W2, BIAS);
    win_attn<<<2048, 512, SMEM_BYTES, stream>>>(x, W1, qkv_b, W2, proj_b, BIAS, outp);
}